// Round 12
// baseline (482.310 us; speedup 1.0000x reference)
//
#include <hip/hip_runtime.h>
#include <hip/hip_cooperative_groups.h>
namespace cg = cooperative_groups;

#define NEG_SLOPE 0.2f
static constexpr int IN_F = 128;   // input feature dim
static constexpr int NHEAD = 4;
static constexpr int CH = 64;      // channels per head
static constexpr int HC = 256;     // NHEAD*CH
static constexpr int SC_EPB = 2000;  // edges per scatter job
static constexpr int CB_CAP = 6144;  // csr LDS sort capacity
static constexpr int CPAD = 16;      // counter pad: 1 counter per 64B line
static constexpr int PBC = 416;      // count slices

static __host__ size_t align256(size_t v) { return (v + 255) & ~((size_t)255); }

__device__ inline ushort f2bf(float f) {          // round-to-nearest-even fp32->bf16
    unsigned u = __float_as_uint(f);
    unsigned r = u + 0x7FFFu + ((u >> 16) & 1u);
    return (ushort)(r >> 16);
}
__device__ inline float bf2f(ushort s) { return __uint_as_float(((unsigned)s) << 16); }

typedef short s16x8 __attribute__((ext_vector_type(8)));    // 8 bf16 = 4 VGPR
typedef float f32x16 __attribute__((ext_vector_type(16)));  // 32x32 accumulator

// ============ ONE cooperative kernel for stages 0-3 =========================
// P0: zero counters + Wt transpose; P1: bucket count; P2: scatter (LDS sort);
// P3: MFMA GEMM (B direct from L2-resident Wt, no Bs tile) || csr finalize.
// grid.sync() between phases replaces 4 dispatch boundaries.
__global__ __launch_bounds__(256, 4) void fused_prep_kernel(
    const float* __restrict__ x, const float* __restrict__ W,
    ushort* __restrict__ Wt,
    const float* __restrict__ att_src, const float* __restrict__ att_dst,
    ushort* __restrict__ hb, float* __restrict__ a_src, float* __restrict__ a_dst,
    const int* __restrict__ src, const int* __restrict__ dst,
    int* __restrict__ ccnt, int* __restrict__ cur0,
    unsigned* __restrict__ ebuf, int* __restrict__ rowptr, int* __restrict__ csr_src,
    int N, int E, int Etot, int NB, int NTB, int epbc, int PBS)
{
    constexpr int LDK = 136;
    __shared__ __align__(16) char smem[27648];   // union: As(17.4K)/scatter(14.6K)/csr(27.6K)
    __shared__ int ebs[257];                     // persistent exclusive bucket bases
    cg::grid_group grd = cg::this_grid();
    const int t = threadIdx.x;
    const int gsz = gridDim.x * 256;
    const int gtid = blockIdx.x * 256 + t;

    // ---------------- P0: zero counters + Wt transpose ----------------------
    for (int i = gtid; i < 256 * CPAD; i += gsz) { ccnt[i] = 0; cur0[i] = 0; }
    for (int f = gtid; f < IN_F * HC; f += gsz) {
        int k = f >> 8, n = f & 255;
        Wt[n * IN_F + k] = f2bf(W[(size_t)k * HC + n]);
    }
    if (gtid == 0) rowptr[N] = Etot;
    __threadfence();
    grd.sync();

    // ---------------- P1: bucket count --------------------------------------
    {
        int* hist = (int*)smem;
        for (int job = blockIdx.x; job < PBC; job += gridDim.x) {
            __syncthreads();
            hist[t] = 0;
            __syncthreads();
            int lo = job * epbc, hi = min(E, lo + epbc);
            for (int i = lo + t; i < hi; i += 256)
                atomicAdd(&hist[((unsigned)dst[i]) >> 8], 1);
            __syncthreads();
            if (t < NB && hist[t]) atomicAdd(&ccnt[t * CPAD], hist[t]);
        }
    }
    __threadfence();
    grd.sync();

    // ---------------- P2: ebs scan (every block) + scatter ------------------
    {
        int* scn = (int*)smem;
        int cv = ccnt[t * CPAD];
        scn[t] = cv;
        __syncthreads();
        #pragma unroll
        for (int off = 1; off < 256; off <<= 1) {
            int a = scn[t];
            int b = (t >= off) ? scn[t - off] : 0;
            __syncthreads();
            scn[t] = a + b;
            __syncthreads();
        }
        ebs[t] = scn[t] - cv;
        if (t == 255) ebs[256] = scn[255];
        __syncthreads();

        int* hist  = (int*)smem;
        int* lbase = (int*)(smem + 1024);
        int* gbase = (int*)(smem + 2048);
        int* cur   = (int*)(smem + 3072);
        unsigned* sbuf = (unsigned*)(smem + 4096);
        unsigned char* tb = (unsigned char*)(smem + 4096 + (SC_EPB + 48) * 4);
        for (int job = blockIdx.x; job < PBS; job += gridDim.x) {
            __syncthreads();
            hist[t] = 0;
            __syncthreads();
            int lo = job * SC_EPB;
            int hi = min(E, lo + SC_EPB);
            int cnt = hi - lo;
            unsigned pk[8]; int bk[8];
            #pragma unroll
            for (int u = 0; u < 8; ++u) {
                int i = lo + t + 256 * u;
                bk[u] = -1;
                if (i < hi) {
                    unsigned d = (unsigned)dst[i];
                    bk[u] = (int)(d >> 8);
                    pk[u] = (((unsigned)src[i]) << 8) | (d & 255u);
                    atomicAdd(&hist[bk[u]], 1);
                }
            }
            __syncthreads();
            int v = hist[t];
            lbase[t] = v;
            __syncthreads();
            #pragma unroll
            for (int off = 1; off < 256; off <<= 1) {
                int a = lbase[t];
                int b = (t >= off) ? lbase[t - off] : 0;
                __syncthreads();
                lbase[t] = a + b;
                __syncthreads();
            }
            int excl = lbase[t] - v;
            if (v) gbase[t] = ebs[t] + atomicAdd(&cur0[t * CPAD], v);
            __syncthreads();
            lbase[t] = excl;
            cur[t] = excl;
            __syncthreads();
            #pragma unroll
            for (int u = 0; u < 8; ++u) {
                if (bk[u] >= 0) {
                    int p = atomicAdd(&cur[bk[u]], 1);
                    sbuf[p] = pk[u];
                    tb[p] = (unsigned char)bk[u];
                }
            }
            __syncthreads();
            for (int j = t; j < cnt; j += 256) {
                int b = tb[j];
                ebuf[gbase[b] + j - lbase[b]] = sbuf[j];
            }
        }
    }
    __threadfence();
    grd.sync();

    // ---------------- P3: GEMM tiles || CSR buckets --------------------------
    {
        int njobs = NTB * 2 + NB;
        for (int job = blockIdx.x; job < njobs; job += gridDim.x) {
            __syncthreads();
            if (job < NTB * 2) {        // ---- GEMM job: 64 rows x 128 cols ----
                ushort* As = (ushort*)smem;
                int m0 = (job >> 1) * 64;
                int jy = job & 1;
                int n0 = jy * 128;
                #pragma unroll
                for (int u = 0; u < 8; ++u) {
                    int f = t + 256 * u;
                    int r = f >> 5;
                    int k4 = (f & 31) * 4;
                    int row = m0 + r;
                    float4 v = make_float4(0.f, 0.f, 0.f, 0.f);
                    if (row < N) v = *(const float4*)(x + (size_t)row * IN_F + k4);
                    ushort4 o;
                    o.x = f2bf(v.x); o.y = f2bf(v.y); o.z = f2bf(v.z); o.w = f2bf(v.w);
                    *(ushort4*)&As[r * LDK + k4] = o;
                }
                __syncthreads();
                int w = t >> 6, lane = t & 63;
                int mrow = 32 * (w >> 1) + (lane & 31);
                int nbg = n0 + 64 * (w & 1) + (lane & 31);
                int kq = (lane >> 5) * 8;
                f32x16 acc0 = {}, acc1 = {};
                #pragma unroll
                for (int s = 0; s < 8; ++s) {
                    s16x8 af = *(const s16x8*)&As[mrow * LDK + 16 * s + kq];
                    s16x8 b0 = *(const s16x8*)(Wt + (size_t)nbg * IN_F + 16 * s + kq);
                    s16x8 b1 = *(const s16x8*)(Wt + (size_t)(nbg + 32) * IN_F + 16 * s + kq);
                    acc0 = __builtin_amdgcn_mfma_f32_32x32x16_bf16(af, b0, acc0, 0, 0, 0);
                    acc1 = __builtin_amdgcn_mfma_f32_32x32x16_bf16(af, b1, acc1, 0, 0, 0);
                }
                __syncthreads();
                ushort* Hs = As;
                {
                    int rbase = 4 * (lane >> 5) + 32 * (w >> 1);
                    int c0 = 64 * (w & 1) + (lane & 31);
                    #pragma unroll
                    for (int r = 0; r < 16; ++r) {
                        int rowL = rbase + (r & 3) + 8 * (r >> 2);
                        Hs[rowL * LDK + c0]      = f2bf(acc0[r]);
                        Hs[rowL * LDK + c0 + 32] = f2bf(acc1[r]);
                    }
                }
                __syncthreads();
                {
                    int r2 = t >> 2;
                    int q = t & 3;
                    int row = m0 + r2;
                    uint4 p0 = *(const uint4*)&Hs[r2 * LDK + 32 * q];
                    uint4 p1 = *(const uint4*)&Hs[r2 * LDK + 32 * q + 8];
                    uint4 p2 = *(const uint4*)&Hs[r2 * LDK + 32 * q + 16];
                    uint4 p3 = *(const uint4*)&Hs[r2 * LDK + 32 * q + 24];
                    if (row < N) {
                        ushort* dsth = hb + (size_t)row * HC + n0 + 32 * q;
                        *(uint4*)(dsth)      = p0;
                        *(uint4*)(dsth + 8)  = p1;
                        *(uint4*)(dsth + 16) = p2;
                        *(uint4*)(dsth + 24) = p3;
                    }
                    int hq = 2 * jy + (q >> 1);
                    int cb = (q & 1) * 32;
                    const float* asp = att_src + hq * CH + cb;
                    const float* adp = att_dst + hq * CH + cb;
                    unsigned uu[16] = { p0.x, p0.y, p0.z, p0.w, p1.x, p1.y, p1.z, p1.w,
                                        p2.x, p2.y, p2.z, p2.w, p3.x, p3.y, p3.z, p3.w };
                    float ps = 0.f, pd = 0.f;
                    #pragma unroll
                    for (int i = 0; i < 16; ++i) {
                        float lo = bf2f((ushort)(uu[i] & 0xFFFFu));
                        float hi = bf2f((ushort)(uu[i] >> 16));
                        ps += lo * asp[2 * i] + hi * asp[2 * i + 1];
                        pd += lo * adp[2 * i] + hi * adp[2 * i + 1];
                    }
                    ps += __shfl_xor(ps, 1, 64);
                    pd += __shfl_xor(pd, 1, 64);
                    if ((q & 1) == 0 && row < N) {
                        a_src[(size_t)row * NHEAD + hq] = ps;
                        a_dst[(size_t)row * NHEAD + hq] = pd;
                    }
                }
            } else {                    // ---- CSR bucket job ----
                int b = job - NTB * 2;
                int* scn = (int*)smem;
                int* hist = (int*)(smem + 1024);
                int* cur = (int*)(smem + 2048);
                unsigned* srt = (unsigned*)(smem + 3072);
                int lo = ebs[b], hi = ebs[b + 1];
                int n0 = b << 8;
                int ncnt = min(256, N - n0);
                int cnt = hi - lo;
                int cb = lo + n0;       // global csr base (n0 = self loops before)
                hist[t] = 0;
                __syncthreads();
                for (int i = lo + t; i < hi; i += 256)
                    atomicAdd(&hist[ebuf[i] & 255u], 1);
                __syncthreads();
                int v = hist[t];
                scn[t] = v;
                __syncthreads();
                #pragma unroll
                for (int off = 1; off < 256; off <<= 1) {
                    int a = scn[t];
                    int bb = (t >= off) ? scn[t - off] : 0;
                    __syncthreads();
                    scn[t] = a + bb;
                    __syncthreads();
                }
                int excl = scn[t] - v;
                if (t < ncnt) {
                    int seg = cb + excl + t;    // +t = self loops of prior nodes
                    rowptr[n0 + t] = seg;
                    csr_src[seg] = n0 + t;      // self loop first
                }
                cur[t] = excl;
                __syncthreads();
                if (cnt <= CB_CAP) {
                    for (int i = lo + t; i < hi; i += 256) {
                        unsigned e = ebuf[i];
                        int p = atomicAdd(&cur[e & 255u], 1);
                        srt[p] = e;
                    }
                    __syncthreads();
                    for (int j = t; j < cnt; j += 256) {
                        unsigned e = srt[j];
                        csr_src[cb + j + (int)(e & 255u) + 1] = (int)(e >> 8);
                    }
                } else {                // fallback (oversized bucket)
                    for (int i = lo + t; i < hi; i += 256) {
                        unsigned e = ebuf[i];
                        int ln = (int)(e & 255u);
                        int p = atomicAdd(&cur[ln], 1);
                        csr_src[cb + p + ln + 1] = (int)(e >> 8);
                    }
                }
            }
        }
    }
}

// ===================== fallback kernels (non-cooperative path) ===============
__global__ __launch_bounds__(256) void fb_prep_count(
    const float* __restrict__ W, ushort* __restrict__ Wt,
    const int* __restrict__ dst, int* __restrict__ ccnt, int* __restrict__ cur0,
    int* __restrict__ rowptr, int N, int Etot, int E, int epb, int NB)
{
    __shared__ int hist[256];
    int t = threadIdx.x;
    if (blockIdx.x < 128) {             // Wt transpose + counter zero
        int f = blockIdx.x * 256 + t;
        int k = f >> 8, n = f & 255;
        Wt[n * IN_F + k] = f2bf(W[(size_t)k * HC + n]);
        if (f < 256 * CPAD) { ccnt[f] = 0; cur0[f] = 0; }
        if (f == 0) rowptr[N] = Etot;
        return;
    }
    hist[t] = 0;
    __syncthreads();
    int slice = blockIdx.x - 128;
    int lo = slice * epb, hi = min(E, lo + epb);
    for (int i = lo + t; i < hi; i += 256)
        atomicAdd(&hist[((unsigned)dst[i]) >> 8], 1);
    __syncthreads();
    if (t < NB && hist[t]) atomicAdd(&ccnt[t * CPAD], hist[t]);
}
// NOTE: fallback count must run AFTER zeroing -> use two dispatches there.

__global__ __launch_bounds__(256) void fb_scatter(
    const int* __restrict__ src, const int* __restrict__ dst,
    const int* __restrict__ ccnt, int* __restrict__ cur0,
    unsigned* __restrict__ ebuf, int E)
{
    __shared__ int eb[256];
    __shared__ int hist[256];
    __shared__ int lbase[256];
    __shared__ int gbase[256];
    __shared__ int cur[256];
    __shared__ unsigned sbuf[SC_EPB + 48];
    __shared__ unsigned char tb[SC_EPB + 48];
    int t = threadIdx.x;
    int cv = ccnt[t * CPAD];
    eb[t] = cv;
    __syncthreads();
    #pragma unroll
    for (int off = 1; off < 256; off <<= 1) {
        int a = eb[t];
        int b = (t >= off) ? eb[t - off] : 0;
        __syncthreads();
        eb[t] = a + b;
        __syncthreads();
    }
    int myeb = eb[t] - cv;
    __syncthreads();
    eb[t] = myeb;
    int lo = blockIdx.x * SC_EPB;
    int hi = min(E, lo + SC_EPB);
    int cnt = hi - lo;
    hist[t] = 0;
    __syncthreads();
    unsigned pk[8]; int bk[8];
    #pragma unroll
    for (int u = 0; u < 8; ++u) {
        int i = lo + t + 256 * u;
        bk[u] = -1;
        if (i < hi) {
            unsigned d = (unsigned)dst[i];
            bk[u] = (int)(d >> 8);
            pk[u] = (((unsigned)src[i]) << 8) | (d & 255u);
            atomicAdd(&hist[bk[u]], 1);
        }
    }
    __syncthreads();
    int v = hist[t];
    lbase[t] = v;
    __syncthreads();
    #pragma unroll
    for (int off = 1; off < 256; off <<= 1) {
        int a = lbase[t];
        int b = (t >= off) ? lbase[t - off] : 0;
        __syncthreads();
        lbase[t] = a + b;
        __syncthreads();
    }
    int excl = lbase[t] - v;
    if (v) gbase[t] = eb[t] + atomicAdd(&cur0[t * CPAD], v);
    __syncthreads();
    lbase[t] = excl;
    cur[t] = excl;
    __syncthreads();
    #pragma unroll
    for (int u = 0; u < 8; ++u) {
        if (bk[u] >= 0) {
            int p = atomicAdd(&cur[bk[u]], 1);
            sbuf[p] = pk[u];
            tb[p] = (unsigned char)bk[u];
        }
    }
    __syncthreads();
    for (int j = t; j < cnt; j += 256) {
        int b = tb[j];
        ebuf[gbase[b] + j - lbase[b]] = sbuf[j];
    }
}

__global__ __launch_bounds__(256) void fb_gemm_csr(
    const float* __restrict__ x, const ushort* __restrict__ Wt,
    const float* __restrict__ att_src, const float* __restrict__ att_dst,
    ushort* __restrict__ hb, float* __restrict__ a_src, float* __restrict__ a_dst,
    const unsigned* __restrict__ ebuf, const int* __restrict__ ccnt,
    int* __restrict__ rowptr, int* __restrict__ csr_src,
    int NTB, int NB, int N)
{
    constexpr int LDK = 136;
    __shared__ __align__(16) char smem[27648];
    const int t = threadIdx.x;
    if (blockIdx.x >= NTB * 2) {        // csr role
        int b = blockIdx.x - NTB * 2;
        if (b >= NB) return;
        int* scn = (int*)smem;
        int* hist = (int*)(smem + 1024);
        int* cur = (int*)(smem + 2048);
        unsigned* srt = (unsigned*)(smem + 3072);
        int cv = ccnt[t * CPAD];
        scn[t] = cv;
        __syncthreads();
        #pragma unroll
        for (int off = 1; off < 256; off <<= 1) {
            int a = scn[t];
            int bb = (t >= off) ? scn[t - off] : 0;
            __syncthreads();
            scn[t] = a + bb;
            __syncthreads();
        }
        int lo = (b == 0) ? 0 : scn[b - 1];
        int hi = scn[b];
        __syncthreads();
        int n0 = b << 8;
        int ncnt = min(256, N - n0);
        int cnt = hi - lo;
        int cb = lo + n0;
        hist[t] = 0;
        __syncthreads();
        for (int i = lo + t; i < hi; i += 256)
            atomicAdd(&hist[ebuf[i] & 255u], 1);
        __syncthreads();
        int v = hist[t];
        scn[t] = v;
        __syncthreads();
        #pragma unroll
        for (int off = 1; off < 256; off <<= 1) {
            int a = scn[t];
            int bb = (t >= off) ? scn[t - off] : 0;
            __syncthreads();
            scn[t] = a + bb;
            __syncthreads();
        }
        int excl = scn[t] - v;
        if (t < ncnt) {
            int seg = cb + excl + t;
            rowptr[n0 + t] = seg;
            csr_src[seg] = n0 + t;
        }
        cur[t] = excl;
        __syncthreads();
        if (cnt <= CB_CAP) {
            for (int i = lo + t; i < hi; i += 256) {
                unsigned e = ebuf[i];
                int p = atomicAdd(&cur[e & 255u], 1);
                srt[p] = e;
            }
            __syncthreads();
            for (int j = t; j < cnt; j += 256) {
                unsigned e = srt[j];
                csr_src[cb + j + (int)(e & 255u) + 1] = (int)(e >> 8);
            }
        } else {
            for (int i = lo + t; i < hi; i += 256) {
                unsigned e = ebuf[i];
                int ln = (int)(e & 255u);
                int p = atomicAdd(&cur[ln], 1);
                csr_src[cb + p + ln + 1] = (int)(e >> 8);
            }
        }
        return;
    }
    // gemm role (B direct from Wt)
    ushort* As = (ushort*)smem;
    int m0 = (blockIdx.x >> 1) * 64;
    int jy = blockIdx.x & 1;
    int n0 = jy * 128;
    #pragma unroll
    for (int u = 0; u < 8; ++u) {
        int f = t + 256 * u;
        int r = f >> 5;
        int k4 = (f & 31) * 4;
        int row = m0 + r;
        float4 v = make_float4(0.f, 0.f, 0.f, 0.f);
        if (row < N) v = *(const float4*)(x + (size_t)row * IN_F + k4);
        ushort4 o;
        o.x = f2bf(v.x); o.y = f2bf(v.y); o.z = f2bf(v.z); o.w = f2bf(v.w);
        *(ushort4*)&As[r * LDK + k4] = o;
    }
    __syncthreads();
    int w = t >> 6, lane = t & 63;
    int mrow = 32 * (w >> 1) + (lane & 31);
    int nbg = n0 + 64 * (w & 1) + (lane & 31);
    int kq = (lane >> 5) * 8;
    f32x16 acc0 = {}, acc1 = {};
    #pragma unroll
    for (int s = 0; s < 8; ++s) {
        s16x8 af = *(const s16x8*)&As[mrow * LDK + 16 * s + kq];
        s16x8 b0 = *(const s16x8*)(Wt + (size_t)nbg * IN_F + 16 * s + kq);
        s16x8 b1 = *(const s16x8*)(Wt + (size_t)(nbg + 32) * IN_F + 16 * s + kq);
        acc0 = __builtin_amdgcn_mfma_f32_32x32x16_bf16(af, b0, acc0, 0, 0, 0);
        acc1 = __builtin_amdgcn_mfma_f32_32x32x16_bf16(af, b1, acc1, 0, 0, 0);
    }
    __syncthreads();
    ushort* Hs = As;
    {
        int rbase = 4 * (lane >> 5) + 32 * (w >> 1);
        int c0 = 64 * (w & 1) + (lane & 31);
        #pragma unroll
        for (int r = 0; r < 16; ++r) {
            int rowL = rbase + (r & 3) + 8 * (r >> 2);
            Hs[rowL * LDK + c0]      = f2bf(acc0[r]);
            Hs[rowL * LDK + c0 + 32] = f2bf(acc1[r]);
        }
    }
    __syncthreads();
    {
        int r2 = t >> 2;
        int q = t & 3;
        int row = m0 + r2;
        uint4 p0 = *(const uint4*)&Hs[r2 * LDK + 32 * q];
        uint4 p1 = *(const uint4*)&Hs[r2 * LDK + 32 * q + 8];
        uint4 p2 = *(const uint4*)&Hs[r2 * LDK + 32 * q + 16];
        uint4 p3 = *(const uint4*)&Hs[r2 * LDK + 32 * q + 24];
        if (row < N) {
            ushort* dsth = hb + (size_t)row * HC + n0 + 32 * q;
            *(uint4*)(dsth)      = p0;
            *(uint4*)(dsth + 8)  = p1;
            *(uint4*)(dsth + 16) = p2;
            *(uint4*)(dsth + 24) = p3;
        }
        int hq = 2 * jy + (q >> 1);
        int cb = (q & 1) * 32;
        const float* asp = att_src + hq * CH + cb;
        const float* adp = att_dst + hq * CH + cb;
        unsigned uu[16] = { p0.x, p0.y, p0.z, p0.w, p1.x, p1.y, p1.z, p1.w,
                            p2.x, p2.y, p2.z, p2.w, p3.x, p3.y, p3.z, p3.w };
        float ps = 0.f, pd = 0.f;
        #pragma unroll
        for (int i = 0; i < 16; ++i) {
            float lo = bf2f((ushort)(uu[i] & 0xFFFFu));
            float hi = bf2f((ushort)(uu[i] >> 16));
            ps += lo * asp[2 * i] + hi * asp[2 * i + 1];
            pd += lo * adp[2 * i] + hi * adp[2 * i + 1];
        }
        ps += __shfl_xor(ps, 1, 64);
        pd += __shfl_xor(pd, 1, 64);
        if ((q & 1) == 0 && row < N) {
            a_src[(size_t)row * NHEAD + hq] = ps;
            a_dst[(size_t)row * NHEAD + hq] = pd;
        }
    }
}

// ------------- single-pass softmax aggregate (unchanged, 66us config) -------
__global__ __launch_bounds__(256) void aggregate_kernel(
    const ushort* __restrict__ hb, const float* __restrict__ a_src,
    const float* __restrict__ a_dst, const int* __restrict__ rowptr,
    const int* __restrict__ csr_src, const float* __restrict__ bias,
    float* __restrict__ out, int N)
{
    int node = (int)((blockIdx.x * (size_t)blockDim.x + threadIdx.x) >> 6);
    int l = threadIdx.x & 63;
    if (node >= N) return;
    int start = rowptr[node];
    int end = rowptr[node + 1];
    int hd = l >> 4;
    float adh = a_dst[(size_t)node * NHEAD + hd];

    float4 acc0 = make_float4(0.f, 0.f, 0.f, 0.f);
    float4 acc1 = make_float4(0.f, 0.f, 0.f, 0.f);
    float4 acc2 = make_float4(0.f, 0.f, 0.f, 0.f);
    float4 acc3 = make_float4(0.f, 0.f, 0.f, 0.f);
    float s0 = 0.f, s1 = 0.f, s2 = 0.f, s3 = 0.f;

    int k = start;
    for (; k + 4 <= end; k += 4) {
        int sj0 = csr_src[k];
        int sj1 = csr_src[k + 1];
        int sj2 = csr_src[k + 2];
        int sj3 = csr_src[k + 3];
        float a0 = a_src[(size_t)sj0 * NHEAD + hd];
        float a1 = a_src[(size_t)sj1 * NHEAD + hd];
        float a2 = a_src[(size_t)sj2 * NHEAD + hd];
        float a3 = a_src[(size_t)sj3 * NHEAD + hd];
        ushort4 h0 = *(const ushort4*)(hb + ((size_t)sj0 << 8) + 4 * l);
        ushort4 h1 = *(const ushort4*)(hb + ((size_t)sj1 << 8) + 4 * l);
        ushort4 h2 = *(const ushort4*)(hb + ((size_t)sj2 << 8) + 4 * l);
        ushort4 h3 = *(const ushort4*)(hb + ((size_t)sj3 << 8) + 4 * l);
        float e0 = a0 + adh; e0 = fmaxf(e0, NEG_SLOPE * e0); float w0 = __expf(e0);
        float e1 = a1 + adh; e1 = fmaxf(e1, NEG_SLOPE * e1); float w1 = __expf(e1);
        float e2 = a2 + adh; e2 = fmaxf(e2, NEG_SLOPE * e2); float w2 = __expf(e2);
        float e3 = a3 + adh; e3 = fmaxf(e3, NEG_SLOPE * e3); float w3 = __expf(e3);
        s0 += w0; s1 += w1; s2 += w2; s3 += w3;
        acc0.x += w0 * bf2f(h0.x); acc0.y += w0 * bf2f(h0.y);
        acc0.z += w0 * bf2f(h0.z); acc0.w += w0 * bf2f(h0.w);
        acc1.x += w1 * bf2f(h1.x); acc1.y += w1 * bf2f(h1.y);
        acc1.z += w1 * bf2f(h1.z); acc1.w += w1 * bf2f(h1.w);
        acc2.x += w2 * bf2f(h2.x); acc2.y += w2 * bf2f(h2.y);
        acc2.z += w2 * bf2f(h2.z); acc2.w += w2 * bf2f(h2.w);
        acc3.x += w3 * bf2f(h3.x); acc3.y += w3 * bf2f(h3.y);
        acc3.z += w3 * bf2f(h3.z); acc3.w += w3 * bf2f(h3.w);
    }
    for (; k < end; ++k) {                       // tail (<=3 edges)
        int sj0 = csr_src[k];
        float a0 = a_src[(size_t)sj0 * NHEAD + hd];
        ushort4 h0 = *(const ushort4*)(hb + ((size_t)sj0 << 8) + 4 * l);
        float e0 = a0 + adh; e0 = fmaxf(e0, NEG_SLOPE * e0);
        float w0 = __expf(e0);
        s0 += w0;
        acc0.x += w0 * bf2f(h0.x); acc0.y += w0 * bf2f(h0.y);
        acc0.z += w0 * bf2f(h0.z); acc0.w += w0 * bf2f(h0.w);
    }

    float inv = 1.0f / (s0 + s1 + s2 + s3);
    float4 acc;
    acc.x = (acc0.x + acc1.x + acc2.x + acc3.x) * inv;
    acc.y = (acc0.y + acc1.y + acc2.y + acc3.y) * inv;
    acc.z = (acc0.z + acc1.z + acc2.z + acc3.z) * inv;
    acc.w = (acc0.w + acc1.w + acc2.w + acc3.w) * inv;

    #pragma unroll
    for (int off = 16; off < 64; off <<= 1) {
        acc.x += __shfl_xor(acc.x, off, 64);
        acc.y += __shfl_xor(acc.y, off, 64);
        acc.z += __shfl_xor(acc.z, off, 64);
        acc.w += __shfl_xor(acc.w, off, 64);
    }
    if (l < 16) {
        float4 b4 = *(const float4*)(bias + 4 * l);
        float4 o;
        o.x = acc.x * 0.25f + b4.x;
        o.y = acc.y * 0.25f + b4.y;
        o.z = acc.z * 0.25f + b4.z;
        o.w = acc.w * 0.25f + b4.w;
        o.x = (o.x > 0.f) ? o.x : (__expf(o.x) - 1.f);
        o.y = (o.y > 0.f) ? o.y : (__expf(o.y) - 1.f);
        o.z = (o.z > 0.f) ? o.z : (__expf(o.z) - 1.f);
        o.w = (o.w > 0.f) ? o.w : (__expf(o.w) - 1.f);
        *(float4*)(out + (size_t)node * CH + 4 * l) = o;
    }
}

extern "C" void kernel_launch(void* const* d_in, const int* in_sizes, int n_in,
                              void* d_out, int out_size, void* d_ws, size_t ws_size,
                              hipStream_t stream)
{
    const float* x         = (const float*)d_in[0];
    const int*   edge_idx  = (const int*)d_in[1];
    const float* W         = (const float*)d_in[2];
    const float* att_src   = (const float*)d_in[3];
    const float* att_dst   = (const float*)d_in[4];
    const float* bias      = (const float*)d_in[5];
    float* out = (float*)d_out;

    int N = in_sizes[0] / IN_F;
    int E = in_sizes[1] / 2;
    int Etot = E + N;
    int NB = (N + 255) >> 8;           // coarse buckets (assumes N <= 65536)
    const int* srcp = edge_idx;
    const int* dstp = edge_idx + E;

    char* ws = (char*)d_ws;
    size_t off = 0;
    ushort*  hb     = (ushort*)(ws + off);   off += align256((size_t)N * HC * sizeof(ushort));
    ushort*  Wt     = (ushort*)(ws + off);   off += align256((size_t)HC * IN_F * sizeof(ushort));
    float*   a_src  = (float*)(ws + off);    off += align256((size_t)N * NHEAD * sizeof(float));
    float*   a_dst  = (float*)(ws + off);    off += align256((size_t)N * NHEAD * sizeof(float));
    int*     ccnt   = (int*)(ws + off);      off += align256(256 * CPAD * sizeof(int));
    int*     cur0   = (int*)(ws + off);      off += align256(256 * CPAD * sizeof(int));
    unsigned* ebuf  = (unsigned*)(ws + off); off += align256((size_t)E * sizeof(unsigned));
    int*     rowptr = (int*)(ws + off);      off += align256(((size_t)N + 1) * sizeof(int));
    int*     csrs   = (int*)(ws + off);      off += align256((size_t)Etot * sizeof(int));
    (void)ws_size; (void)n_in; (void)out_size;

    int NTB = (N + 63) / 64;
    int epbc = (E + PBC - 1) / PBC;
    int PBS = (E + SC_EPB - 1) / SC_EPB;

    // cooperative grid size: co-resident blocks only
    int nbpc = 0;
    hipOccupancyMaxActiveBlocksPerMultiprocessor(&nbpc, fused_prep_kernel, 256, 0);
    if (nbpc < 1) nbpc = 1;
    int ncu = 256;
    hipDeviceProp_t prop;
    int dev = 0;
    if (hipGetDevice(&dev) == hipSuccess &&
        hipGetDeviceProperties(&prop, dev) == hipSuccess)
        ncu = prop.multiProcessorCount;
    int grid = nbpc * ncu;
    int maxjobs = NTB * 2 + NB;
    if (grid > maxjobs) grid = maxjobs;

    void* args[] = {
        (void*)&x, (void*)&W, (void*)&Wt, (void*)&att_src, (void*)&att_dst,
        (void*)&hb, (void*)&a_src, (void*)&a_dst, (void*)&srcp, (void*)&dstp,
        (void*)&ccnt, (void*)&cur0, (void*)&ebuf, (void*)&rowptr, (void*)&csrs,
        (void*)&N, (void*)&E, (void*)&Etot, (void*)&NB, (void*)&NTB,
        (void*)&epbc, (void*)&PBS
    };
    hipError_t cerr = hipLaunchCooperativeKernel(
        (const void*)fused_prep_kernel, dim3(grid), dim3(256), args, 0, stream);

    if (cerr != hipSuccess) {
        // -------- fallback: non-cooperative pipeline (R11-equivalent) --------
        hipMemsetAsync(ccnt, 0, 256 * CPAD * sizeof(int), stream);
        hipMemsetAsync(cur0, 0, 256 * CPAD * sizeof(int), stream);
        int epbf = (E + PBC - 1) / PBC;
        fb_prep_count<<<128 + PBC, 256, 0, stream>>>(
            W, Wt, dstp, ccnt, cur0, rowptr, N, Etot, E, epbf, NB);
        fb_scatter<<<PBS, 256, 0, stream>>>(srcp, dstp, ccnt, cur0, ebuf, E);
        fb_gemm_csr<<<NTB * 2 + NB, 256, 0, stream>>>(
            x, Wt, att_src, att_dst, hb, a_src, a_dst, ebuf, ccnt,
            rowptr, csrs, NTB, NB, N);
    }

    aggregate_kernel<<<((size_t)N * 64 + 255) / 256, 256, 0, stream>>>(
        hb, a_src, a_dst, rowptr, csrs, bias, out, N);
}

// Round 13
// 205.688 us; speedup vs baseline: 2.3449x; 2.3449x over previous
//
#include <hip/hip_runtime.h>

#define NEG_SLOPE 0.2f
static constexpr int IN_F = 128;   // input feature dim
static constexpr int NHEAD = 4;
static constexpr int CH = 64;      // channels per head
static constexpr int HC = 256;     // NHEAD*CH
static constexpr int SC_EPB = 2000;  // edges per scatter block
static constexpr int CB2_CAP = 4096; // csr_build sub-slice LDS sort capacity
static constexpr int CPAD = 16;      // counter pad: 1 counter per 64B line

static __host__ size_t align256(size_t v) { return (v + 255) & ~((size_t)255); }

__device__ inline ushort f2bf(float f) {          // round-to-nearest-even fp32->bf16
    unsigned u = __float_as_uint(f);
    unsigned r = u + 0x7FFFu + ((u >> 16) & 1u);
    return (ushort)(r >> 16);
}
__device__ inline float bf2f(ushort s) { return __uint_as_float(((unsigned)s) << 16); }

typedef short s16x8 __attribute__((ext_vector_type(8)));    // 8 bf16 = 4 VGPR
typedef float f32x16 __attribute__((ext_vector_type(16)));  // 32x32 accumulator

// ---- prep: Wt[n][k] = bf16(W[k][n]) + zero padded counters + rowptr[N] -----
__global__ __launch_bounds__(256) void prep_kernel(
    const float* __restrict__ W, ushort* __restrict__ Wt,
    int* __restrict__ ccnt, int* __restrict__ cur0,
    int* __restrict__ rowptr, int N, int Etot)
{
    int f = blockIdx.x * 256 + threadIdx.x;     // 32768 elements
    int k = f >> 8;                             // 0..127
    int n = f & 255;                            // 0..255
    Wt[n * IN_F + k] = f2bf(W[(size_t)k * HC + n]);
    if (f < 256 * CPAD) { ccnt[f] = 0; cur0[f] = 0; }
    if (f == 0) rowptr[N] = Etot;
}

// ---- MFMA GEMM (2 heads/block) + fused edge bucket-count -------------------
__global__ __launch_bounds__(256) void gemm_mfma_kernel(
    const float* __restrict__ x, const ushort* __restrict__ Wt,
    const float* __restrict__ att_src, const float* __restrict__ att_dst,
    ushort* __restrict__ hb, float* __restrict__ a_src, float* __restrict__ a_dst,
    const int* __restrict__ dst, int* __restrict__ coarse_cnt,
    int E, int epb, int NTB, int NB, int N)
{
    constexpr int LDK = 136;            // padded K stride (ushort elems)
    __shared__ ushort As[64 * LDK];     // x tile [m][k] bf16
    __shared__ ushort Bs[128 * LDK];    // Wt tile [n][k] bf16
    ushort* Hs = As;                    // h-tile aliases As after MFMA

    const int t = threadIdx.x;

    if (blockIdx.x >= NTB) {            // ---- bucket-count role ----
        int* hist = (int*)As;
        hist[t] = 0;
        __syncthreads();
        int slice = (blockIdx.x - NTB) * 2 + blockIdx.y;
        int lo = slice * epb;
        int hi = min(E, lo + epb);
        for (int i = lo + t; i < hi; i += 256)
            atomicAdd(&hist[((unsigned)dst[i]) >> 8], 1);
        __syncthreads();
        if (t < NB && hist[t]) atomicAdd(&coarse_cnt[t * CPAD], hist[t]);
        return;
    }

    const int m0 = blockIdx.x * 64;
    const int n0 = blockIdx.y * 128;    // col offset in h (2 heads)

    #pragma unroll
    for (int u = 0; u < 8; ++u) {
        int f = t + 256 * u;
        int r = f >> 5;
        int k4 = (f & 31) * 4;
        int row = m0 + r;
        float4 v = make_float4(0.f, 0.f, 0.f, 0.f);
        if (row < N) v = *(const float4*)(x + (size_t)row * IN_F + k4);
        ushort4 o;
        o.x = f2bf(v.x); o.y = f2bf(v.y); o.z = f2bf(v.z); o.w = f2bf(v.w);
        *(ushort4*)&As[r * LDK + k4] = o;
    }
    #pragma unroll
    for (int u = 0; u < 8; ++u) {
        int f = t + 256 * u;
        int n = f >> 4;
        int k8 = (f & 15) * 8;
        uint4 v = *(const uint4*)(Wt + (size_t)(n0 + n) * IN_F + k8);
        *(uint4*)&Bs[n * LDK + k8] = v;
    }
    __syncthreads();

    const int w = t >> 6;
    const int lane = t & 63;
    const int mrow = 32 * (w >> 1) + (lane & 31);
    const int nbase = 64 * (w & 1) + (lane & 31);
    const int kq = (lane >> 5) * 8;

    f32x16 acc0 = {}, acc1 = {};
    #pragma unroll
    for (int s = 0; s < 8; ++s) {
        s16x8 af = *(const s16x8*)&As[mrow * LDK + 16 * s + kq];
        s16x8 b0 = *(const s16x8*)&Bs[nbase * LDK + 16 * s + kq];
        s16x8 b1 = *(const s16x8*)&Bs[(nbase + 32) * LDK + 16 * s + kq];
        acc0 = __builtin_amdgcn_mfma_f32_32x32x16_bf16(af, b0, acc0, 0, 0, 0);
        acc1 = __builtin_amdgcn_mfma_f32_32x32x16_bf16(af, b1, acc1, 0, 0, 0);
    }
    __syncthreads();

    {
        int rbase = 4 * (lane >> 5) + 32 * (w >> 1);
        int c0 = 64 * (w & 1) + (lane & 31);
        #pragma unroll
        for (int r = 0; r < 16; ++r) {
            int rowL = rbase + (r & 3) + 8 * (r >> 2);
            Hs[rowL * LDK + c0]      = f2bf(acc0[r]);
            Hs[rowL * LDK + c0 + 32] = f2bf(acc1[r]);
        }
    }
    __syncthreads();

    {
        int r2 = t >> 2;
        int q = t & 3;
        int row = m0 + r2;
        uint4 p0 = *(const uint4*)&Hs[r2 * LDK + 32 * q];
        uint4 p1 = *(const uint4*)&Hs[r2 * LDK + 32 * q + 8];
        uint4 p2 = *(const uint4*)&Hs[r2 * LDK + 32 * q + 16];
        uint4 p3 = *(const uint4*)&Hs[r2 * LDK + 32 * q + 24];
        if (row < N) {
            ushort* dsth = hb + (size_t)row * HC + n0 + 32 * q;
            *(uint4*)(dsth)      = p0;
            *(uint4*)(dsth + 8)  = p1;
            *(uint4*)(dsth + 16) = p2;
            *(uint4*)(dsth + 24) = p3;
        }
        int hq = 2 * blockIdx.y + (q >> 1);
        int cb = (q & 1) * 32;
        const float* asp = att_src + hq * CH + cb;
        const float* adp = att_dst + hq * CH + cb;
        unsigned uu[16] = { p0.x, p0.y, p0.z, p0.w, p1.x, p1.y, p1.z, p1.w,
                            p2.x, p2.y, p2.z, p2.w, p3.x, p3.y, p3.z, p3.w };
        float ps = 0.f, pd = 0.f;
        #pragma unroll
        for (int i = 0; i < 16; ++i) {
            float lo = bf2f((ushort)(uu[i] & 0xFFFFu));
            float hi = bf2f((ushort)(uu[i] >> 16));
            ps += lo * asp[2 * i] + hi * asp[2 * i + 1];
            pd += lo * adp[2 * i] + hi * adp[2 * i + 1];
        }
        ps += __shfl_xor(ps, 1, 64);
        pd += __shfl_xor(pd, 1, 64);
        if ((q & 1) == 0 && row < N) {
            a_src[(size_t)row * NHEAD + hq] = ps;
            a_dst[(size_t)row * NHEAD + hq] = pd;
        }
    }
}

// pass 3: scatter edges into bucket regions via block-local LDS counting sort.
// Each block re-derives ebase by scanning ccnt. Packed: (src << 8) | (dst&255)
__global__ __launch_bounds__(256) void bucket_scatter(
    const int* __restrict__ src, const int* __restrict__ dst,
    const int* __restrict__ ccnt, int* __restrict__ cur0,
    unsigned* __restrict__ ebuf, int E)
{
    __shared__ int eb[256];             // exclusive base per bucket
    __shared__ int hist[256];
    __shared__ int lbase[256];
    __shared__ int gbase[256];
    __shared__ int cur[256];
    __shared__ unsigned sbuf[SC_EPB + 48];
    __shared__ unsigned char tb[SC_EPB + 48];
    int t = threadIdx.x;
    int cv = ccnt[t * CPAD];
    eb[t] = cv;
    __syncthreads();
    #pragma unroll
    for (int off = 1; off < 256; off <<= 1) {
        int a = eb[t];
        int b = (t >= off) ? eb[t - off] : 0;
        __syncthreads();
        eb[t] = a + b;
        __syncthreads();
    }
    int myebase = eb[t] - cv;
    __syncthreads();
    eb[t] = myebase;

    int lo = blockIdx.x * SC_EPB;
    int hi = min(E, lo + SC_EPB);
    int cnt = hi - lo;
    hist[t] = 0;
    __syncthreads();
    unsigned pk[8]; int bk[8];
    #pragma unroll
    for (int u = 0; u < 8; ++u) {
        int i = lo + t + 256 * u;
        bk[u] = -1;
        if (i < hi) {
            unsigned d = (unsigned)dst[i];
            bk[u] = (int)(d >> 8);
            pk[u] = (((unsigned)src[i]) << 8) | (d & 255u);
            atomicAdd(&hist[bk[u]], 1);
        }
    }
    __syncthreads();
    int v = hist[t];
    lbase[t] = v;
    __syncthreads();
    #pragma unroll
    for (int off = 1; off < 256; off <<= 1) {
        int a = lbase[t];
        int b = (t >= off) ? lbase[t - off] : 0;
        __syncthreads();
        lbase[t] = a + b;
        __syncthreads();
    }
    int excl = lbase[t] - v;
    if (v) gbase[t] = eb[t] + atomicAdd(&cur0[t * CPAD], v);  // reserve run
    __syncthreads();
    lbase[t] = excl;
    cur[t] = excl;
    __syncthreads();
    #pragma unroll
    for (int u = 0; u < 8; ++u) {
        if (bk[u] >= 0) {
            int p = atomicAdd(&cur[bk[u]], 1);
            sbuf[p] = pk[u];
            tb[p] = (unsigned char)bk[u];
        }
    }
    __syncthreads();
    for (int j = t; j < cnt; j += 256) {
        int b = tb[j];
        ebuf[gbase[b] + j - lbase[b]] = sbuf[j];
    }
}

// pass 4: per-bucket CSR finalize, 4 blocks per bucket (64 nodes each).
// Each sub-block histograms the whole bucket but sorts/writes only its own
// 64-node slice -> 4x parallelism (784 blocks) with quartered heavy passes.
__global__ __launch_bounds__(256) void csr_build(
    const unsigned* __restrict__ ebuf, const int* __restrict__ ccnt,
    int* __restrict__ rowptr, int* __restrict__ csr_src, int N)
{
    __shared__ int scn[256];
    __shared__ int hist[256];
    __shared__ int cur[64];
    __shared__ int shd[2];              // [0]=sbase, [1]=send
    __shared__ unsigned srt[CB2_CAP];
    int b = blockIdx.x >> 2;
    int sub = blockIdx.x & 3;
    int t = threadIdx.x;
    // bucket edge range from ccnt scan
    int cv = ccnt[t * CPAD];
    scn[t] = cv;
    __syncthreads();
    #pragma unroll
    for (int off = 1; off < 256; off <<= 1) {
        int a = scn[t];
        int bb = (t >= off) ? scn[t - off] : 0;
        __syncthreads();
        scn[t] = a + bb;
        __syncthreads();
    }
    int lo = (b == 0) ? 0 : scn[b - 1];
    int hi = scn[b];
    __syncthreads();

    int n0b = b << 8;                   // bucket first node
    int sn0 = sub * 64;                 // this slice's first local node
    int ncnt = min(64, N - (n0b + sn0));
    if (ncnt <= 0) return;
    int cnt = hi - lo;
    int cb = lo + n0b;                  // bucket csr base (n0b = self loops before)
    hist[t] = 0;
    __syncthreads();
    for (int i = lo + t; i < hi; i += 256)
        atomicAdd(&hist[ebuf[i] & 255u], 1);
    __syncthreads();
    int v = hist[t];
    scn[t] = v;
    __syncthreads();
    #pragma unroll
    for (int off = 1; off < 256; off <<= 1) {
        int a = scn[t];
        int bb = (t >= off) ? scn[t - off] : 0;
        __syncthreads();
        scn[t] = a + bb;
        __syncthreads();
    }
    int excl = scn[t] - v;
    if (t == sn0) shd[0] = excl;                     // slice edge base
    if (sub < 3) { if (t == sn0 + 64) shd[1] = excl; }
    else if (t == 0) shd[1] = cnt;
    if (t >= sn0 && t < sn0 + ncnt) {   // self loop first in own segments
        int seg = cb + excl + t;
        rowptr[n0b + t] = seg;
        csr_src[seg] = n0b + t;
    }
    __syncthreads();
    int sbase = shd[0];
    int send = shd[1];
    int scnt = send - sbase;            // edges in this slice
    bool fast = (scnt <= CB2_CAP);
    if (t >= sn0 && t < sn0 + 64)
        cur[t - sn0] = fast ? (excl - sbase) : excl;
    __syncthreads();
    if (fast) {                         // LDS sort own slice -> coalesced write
        for (int i = lo + t; i < hi; i += 256) {
            unsigned e = ebuf[i];
            int ln = (int)(e & 255u);
            if ((ln >> 6) == sub) {
                int p = atomicAdd(&cur[ln & 63], 1);
                srt[p] = e;
            }
        }
        __syncthreads();
        for (int j = t; j < scnt; j += 256) {
            unsigned e = srt[j];
            int ln = (int)(e & 255u);
            csr_src[cb + sbase + j + ln + 1] = (int)(e >> 8);
        }
    } else {                            // fallback: direct scatter
        for (int i = lo + t; i < hi; i += 256) {
            unsigned e = ebuf[i];
            int ln = (int)(e & 255u);
            if ((ln >> 6) == sub) {
                int p = atomicAdd(&cur[ln & 63], 1);
                csr_src[cb + p + ln + 1] = (int)(e >> 8);
            }
        }
    }
}

// ------------- single-pass softmax aggregate (no max subtraction) -----------
// Logits e = leaky_relu(a_src+a_dst) are O(±10): exp() cannot overflow fp32.
// One wave per node; lane l: head l>>4, channels 4*(l&15)..+3.
// 4-edge unroll, independent accumulators (best measured config: 65.3us).
__global__ __launch_bounds__(256) void aggregate_kernel(
    const ushort* __restrict__ hb, const float* __restrict__ a_src,
    const float* __restrict__ a_dst, const int* __restrict__ rowptr,
    const int* __restrict__ csr_src, const float* __restrict__ bias,
    float* __restrict__ out, int N)
{
    int node = (int)((blockIdx.x * (size_t)blockDim.x + threadIdx.x) >> 6);
    int l = threadIdx.x & 63;
    if (node >= N) return;
    int start = rowptr[node];
    int end = rowptr[node + 1];
    int hd = l >> 4;
    float adh = a_dst[(size_t)node * NHEAD + hd];

    float4 acc0 = make_float4(0.f, 0.f, 0.f, 0.f);
    float4 acc1 = make_float4(0.f, 0.f, 0.f, 0.f);
    float4 acc2 = make_float4(0.f, 0.f, 0.f, 0.f);
    float4 acc3 = make_float4(0.f, 0.f, 0.f, 0.f);
    float s0 = 0.f, s1 = 0.f, s2 = 0.f, s3 = 0.f;

    int k = start;
    for (; k + 4 <= end; k += 4) {
        int sj0 = csr_src[k];
        int sj1 = csr_src[k + 1];
        int sj2 = csr_src[k + 2];
        int sj3 = csr_src[k + 3];
        float a0 = a_src[(size_t)sj0 * NHEAD + hd];
        float a1 = a_src[(size_t)sj1 * NHEAD + hd];
        float a2 = a_src[(size_t)sj2 * NHEAD + hd];
        float a3 = a_src[(size_t)sj3 * NHEAD + hd];
        ushort4 h0 = *(const ushort4*)(hb + ((size_t)sj0 << 8) + 4 * l);
        ushort4 h1 = *(const ushort4*)(hb + ((size_t)sj1 << 8) + 4 * l);
        ushort4 h2 = *(const ushort4*)(hb + ((size_t)sj2 << 8) + 4 * l);
        ushort4 h3 = *(const ushort4*)(hb + ((size_t)sj3 << 8) + 4 * l);
        float e0 = a0 + adh; e0 = fmaxf(e0, NEG_SLOPE * e0); float w0 = __expf(e0);
        float e1 = a1 + adh; e1 = fmaxf(e1, NEG_SLOPE * e1); float w1 = __expf(e1);
        float e2 = a2 + adh; e2 = fmaxf(e2, NEG_SLOPE * e2); float w2 = __expf(e2);
        float e3 = a3 + adh; e3 = fmaxf(e3, NEG_SLOPE * e3); float w3 = __expf(e3);
        s0 += w0; s1 += w1; s2 += w2; s3 += w3;
        acc0.x += w0 * bf2f(h0.x); acc0.y += w0 * bf2f(h0.y);
        acc0.z += w0 * bf2f(h0.z); acc0.w += w0 * bf2f(h0.w);
        acc1.x += w1 * bf2f(h1.x); acc1.y += w1 * bf2f(h1.y);
        acc1.z += w1 * bf2f(h1.z); acc1.w += w1 * bf2f(h1.w);
        acc2.x += w2 * bf2f(h2.x); acc2.y += w2 * bf2f(h2.y);
        acc2.z += w2 * bf2f(h2.z); acc2.w += w2 * bf2f(h2.w);
        acc3.x += w3 * bf2f(h3.x); acc3.y += w3 * bf2f(h3.y);
        acc3.z += w3 * bf2f(h3.z); acc3.w += w3 * bf2f(h3.w);
    }
    for (; k < end; ++k) {                       // tail (<=3 edges)
        int sj0 = csr_src[k];
        float a0 = a_src[(size_t)sj0 * NHEAD + hd];
        ushort4 h0 = *(const ushort4*)(hb + ((size_t)sj0 << 8) + 4 * l);
        float e0 = a0 + adh; e0 = fmaxf(e0, NEG_SLOPE * e0);
        float w0 = __expf(e0);
        s0 += w0;
        acc0.x += w0 * bf2f(h0.x); acc0.y += w0 * bf2f(h0.y);
        acc0.z += w0 * bf2f(h0.z); acc0.w += w0 * bf2f(h0.w);
    }

    float inv = 1.0f / (s0 + s1 + s2 + s3);      // per-head softmax denominator
    float4 acc;
    acc.x = (acc0.x + acc1.x + acc2.x + acc3.x) * inv;
    acc.y = (acc0.y + acc1.y + acc2.y + acc3.y) * inv;
    acc.z = (acc0.z + acc1.z + acc2.z + acc3.z) * inv;
    acc.w = (acc0.w + acc1.w + acc2.w + acc3.w) * inv;

    // reduce over heads: lanes l, l^16, l^32, l^48 hold same channels
    #pragma unroll
    for (int off = 16; off < 64; off <<= 1) {
        acc.x += __shfl_xor(acc.x, off, 64);
        acc.y += __shfl_xor(acc.y, off, 64);
        acc.z += __shfl_xor(acc.z, off, 64);
        acc.w += __shfl_xor(acc.w, off, 64);
    }
    if (l < 16) {
        float4 b4 = *(const float4*)(bias + 4 * l);
        float4 o;
        o.x = acc.x * 0.25f + b4.x;
        o.y = acc.y * 0.25f + b4.y;
        o.z = acc.z * 0.25f + b4.z;
        o.w = acc.w * 0.25f + b4.w;
        o.x = (o.x > 0.f) ? o.x : (__expf(o.x) - 1.f);
        o.y = (o.y > 0.f) ? o.y : (__expf(o.y) - 1.f);
        o.z = (o.z > 0.f) ? o.z : (__expf(o.z) - 1.f);
        o.w = (o.w > 0.f) ? o.w : (__expf(o.w) - 1.f);
        *(float4*)(out + (size_t)node * CH + 4 * l) = o;
    }
}

extern "C" void kernel_launch(void* const* d_in, const int* in_sizes, int n_in,
                              void* d_out, int out_size, void* d_ws, size_t ws_size,
                              hipStream_t stream)
{
    const float* x         = (const float*)d_in[0];
    const int*   edge_idx  = (const int*)d_in[1];
    const float* W         = (const float*)d_in[2];
    const float* att_src   = (const float*)d_in[3];
    const float* att_dst   = (const float*)d_in[4];
    const float* bias      = (const float*)d_in[5];
    float* out = (float*)d_out;

    const int N = in_sizes[0] / IN_F;
    const int E = in_sizes[1] / 2;
    const int Etot = E + N;
    const int NB = (N + 255) >> 8;     // coarse buckets (assumes N <= 65536)
    const int* srcp = edge_idx;
    const int* dstp = edge_idx + E;

    char* ws = (char*)d_ws;
    size_t off = 0;
    ushort*  hb     = (ushort*)(ws + off);   off += align256((size_t)N * HC * sizeof(ushort));
    ushort*  Wt     = (ushort*)(ws + off);   off += align256((size_t)HC * IN_F * sizeof(ushort));
    float*   a_src  = (float*)(ws + off);    off += align256((size_t)N * NHEAD * sizeof(float));
    float*   a_dst  = (float*)(ws + off);    off += align256((size_t)N * NHEAD * sizeof(float));
    int*     ccnt   = (int*)(ws + off);      off += align256(256 * CPAD * sizeof(int));
    int*     cur0   = (int*)(ws + off);      off += align256(256 * CPAD * sizeof(int));
    unsigned* ebuf  = (unsigned*)(ws + off); off += align256((size_t)E * sizeof(unsigned));
    int*     rowptr = (int*)(ws + off);      off += align256(((size_t)N + 1) * sizeof(int));
    int*     csrs   = (int*)(ws + off);      off += align256((size_t)Etot * sizeof(int));
    (void)ws_size; (void)n_in; (void)out_size;

    const int NTB = (N + 63) / 64;     // gemm tiles
    const int PBC = 208;               // fused count blocks (x2 = 416 slices)
    const int epbc = (E + 2 * PBC - 1) / (2 * PBC);
    const int PBS = (E + SC_EPB - 1) / SC_EPB;   // scatter blocks

    prep_kernel<<<IN_F * HC / 256, 256, 0, stream>>>(W, Wt, ccnt, cur0, rowptr, N, Etot);
    dim3 gg(NTB + PBC, 2);
    gemm_mfma_kernel<<<gg, 256, 0, stream>>>(x, Wt, att_src, att_dst, hb,
                                             a_src, a_dst, dstp, ccnt,
                                             E, epbc, NTB, NB, N);
    bucket_scatter<<<PBS, 256, 0, stream>>>(srcp, dstp, ccnt, cur0, ebuf, E);
    csr_build<<<NB * 4, 256, 0, stream>>>(ebuf, ccnt, rowptr, csrs, N);
    aggregate_kernel<<<((size_t)N * 64 + 255) / 256, 256, 0, stream>>>(
        hb, a_src, a_dst, rowptr, csrs, bias, out, N);
}